// Round 11
// baseline (262.695 us; speedup 1.0000x reference)
//
#include <hip/hip_runtime.h>
#include <math.h>
#include <stdint.h>

// EMACE forward, f32.
// R11 changes vs R10 (mlp_all_k only): 8e x 8c register blocking everywhere
// (2 FLOP per LDS byte, ~halves LDS wave-instructions; kernel is
// LDS-issue-bound). Split-quad thread tiles keep all b128 reads <=2-way:
//   L1-L3: 128 threads, edges {4eq,4eq+64}, cols {4cq,4cq+32}
//   L4:    256 threads/half, cols {4cq,4cq+64} within the 128-col half.

#define PI_F 3.14159265358979323846f
#define ECAP_MAX 72000  // active-edge capacity (expected ~45k)

__device__ __forceinline__ float silu_f(float x) { return x / (1.f + __expf(-x)); }

#define LDSFENCE() asm volatile("s_waitcnt lgkmcnt(0)" ::: "memory")

// ---------------------------------------------------------------- clear
__global__ void clear_k(int* __restrict__ deg, int* __restrict__ cur, int N) {
  int i = blockIdx.x * blockDim.x + threadIdx.x;
  if (i < N) {
    deg[i] = 0;
    cur[i] = 0;
  }
}

// ---------------------------------------------------------------- node init
__global__ void node_init_k(const float* __restrict__ attrs,
                            const float* __restrict__ ae,
                            const float* __restrict__ Wemb,
                            float* __restrict__ h0, int* __restrict__ spec,
                            float* __restrict__ node_e0, int N, int NE) {
  int n = (int)((blockIdx.x * blockDim.x + threadIdx.x) >> 6);
  int lane = threadIdx.x & 63;
  if (n >= N) return;
  const float* a = attrs + (size_t)n * NE;
  int sp = 0;
  for (int e = 0; e < NE; ++e)
    if (a[e] > 0.5f) sp = e;
  h0[(size_t)n * 64 + lane] = Wemb[sp * 64 + lane];
  if (lane == 0) {
    spec[n] = sp;
    node_e0[n] = ae[sp];
  }
}

// ---------------------------------------------------------------- edge pass 1
__global__ void edge_count_k(const float* __restrict__ pos,
                             const float* __restrict__ shifts,
                             const int* __restrict__ ei,
                             int* __restrict__ deg, int E) {
  int e = blockIdx.x * blockDim.x + threadIdx.x;
  if (e >= E) return;
  int s = ei[e], r = ei[E + e];
  float dx = pos[r * 3 + 0] - pos[s * 3 + 0] + shifts[e * 3 + 0];
  float dy = pos[r * 3 + 1] - pos[s * 3 + 1] + shifts[e * 3 + 1];
  float dz = pos[r * 3 + 2] - pos[s * 3 + 2] + shifts[e * 3 + 2];
  float d2 = dx * dx + dy * dy + dz * dz;
  if (d2 < 25.0f) atomicAdd(&deg[r], 1);
}

// ---------------------------------------------------------------- scan
__global__ void scan_deg_k(const int* __restrict__ deg, int* __restrict__ off,
                           int N) {
  __shared__ int sdat[1024];
  int tid = threadIdx.x;
  int chunk = (N + 1023) / 1024;
  int s0 = tid * chunk, s1 = min(s0 + chunk, N);
  int s = 0;
  for (int i = s0; i < s1; ++i) s += deg[i];
  sdat[tid] = s;
  __syncthreads();
  for (int d = 1; d < 1024; d <<= 1) {
    int v = (tid >= d) ? sdat[tid - d] : 0;
    __syncthreads();
    sdat[tid] += v;
    __syncthreads();
  }
  int run = sdat[tid] - s;  // exclusive prefix
  for (int i = s0; i < s1; ++i) {
    off[i] = run;
    run += deg[i];
  }
  if (tid == 1023) off[N] = sdat[1023];
}

// ---------------------------------------------------------------- edge pass 2
__global__ void edge_fill_k(const float* __restrict__ pos,
                            const float* __restrict__ shifts,
                            const int* __restrict__ ei,
                            const int* __restrict__ off, int* __restrict__ cur,
                            int* __restrict__ send, float* __restrict__ Yc,
                            float* __restrict__ fc, int E, int ecap) {
  int e = blockIdx.x * blockDim.x + threadIdx.x;
  if (e >= E) return;
  int s = ei[e], r = ei[E + e];
  float dx = pos[r * 3 + 0] - pos[s * 3 + 0] + shifts[e * 3 + 0];
  float dy = pos[r * 3 + 1] - pos[s * 3 + 1] + shifts[e * 3 + 1];
  float dz = pos[r * 3 + 2] - pos[s * 3 + 2] + shifts[e * 3 + 2];
  float rr = sqrtf(dx * dx + dy * dy + dz * dz + 1e-12f);
  if (rr >= 5.0f) return;  // inactive edge: cutoff=0 -> R=0 -> msg=0
  int p = off[r] + atomicAdd(&cur[r], 1);
  if (p >= ecap) return;  // statistically impossible; memory-safety guard
  send[p] = s;
  float ir = 1.f / rr;
  float x = dx * ir, y = dy * ir, z = dz * ir;
  const float s3 = 1.73205080757f, s5 = 2.23606797750f, s15 = 3.87298334621f;
  const float c70 = 2.09165006634f;   // sqrt(70)/4
  const float c105 = 10.2469507660f;  // sqrt(105)
  const float c42 = 1.62018517460f;   // sqrt(42)/4
  const float c7 = 1.32287565553f;    // sqrt(7)/2
  float* Yp = Yc + (size_t)p * 16;
  float xx = x * x, yy = y * y, zz = z * z;
  Yp[0] = 1.f;
  Yp[1] = s3 * x;
  Yp[2] = s3 * y;
  Yp[3] = s3 * z;
  Yp[4] = s15 * x * y;
  Yp[5] = s15 * y * z;
  Yp[6] = 0.5f * s5 * (3.f * zz - 1.f);
  Yp[7] = s15 * x * z;
  Yp[8] = 0.5f * s15 * (xx - yy);
  Yp[9] = c70 * y * (3.f * xx - yy);
  Yp[10] = c105 * x * y * z;
  Yp[11] = c42 * y * (5.f * zz - 1.f);
  Yp[12] = c7 * z * (5.f * zz - 3.f);
  Yp[13] = c42 * x * (5.f * zz - 1.f);
  Yp[14] = 0.5f * c105 * z * (xx - yy);
  Yp[15] = c70 * x * (xx - 3.f * yy);
  float xr = rr * 0.2f;
  float xr2 = xr * xr, xr4 = xr2 * xr2;
  float xr5 = xr4 * xr, xr6 = xr5 * xr, xr7 = xr6 * xr;
  float poly = 1.f - 21.f * xr5 + 35.f * xr6 - 15.f * xr7;
  float pref = 0.632455532034f /* sqrt(2/5) */ * ir * poly;
  float* fp = fc + (size_t)p * 8;
  // sin(n*pi*xr) via recurrence: s_{n+1} = 2*cos(pi*xr)*s_n - s_{n-1}
  float s1 = sinf(PI_F * xr), c1 = cosf(PI_F * xr);
  float sm = 0.f, sp2 = s1;
  fp[0] = pref * s1;
#pragma unroll
  for (int nb = 2; nb <= 8; ++nb) {
    float sn = 2.f * c1 * sp2 - sm;
    fp[nb - 1] = pref * sn;
    sm = sp2;
    sp2 = sn;
  }
}

// ---------------------------------------------------------------- fused MLP
#define ATILE 128  // edges per block tile
#define SXT 132    // padded sX row stride (floats)

// 8e x 8c GEMM step over K=64: split quads keep b128 reads <=2-way banked.
#define GEMM8x8_STEP(sW, kk, CO2)                                         \
  {                                                                       \
    float4 xA = *(const float4*)&sX[(kk)*SXT + eb1];                      \
    float4 xB = *(const float4*)&sX[(kk)*SXT + eb2];                      \
    float4 wA = *(const float4*)&(sW)[(kk)*64 + cb1];                     \
    float4 wB = *(const float4*)&(sW)[(kk)*64 + cb1 + (CO2)];             \
    float xs[8] = {xA.x, xA.y, xA.z, xA.w, xB.x, xB.y, xB.z, xB.w};       \
    float ws[8] = {wA.x, wA.y, wA.z, wA.w, wB.x, wB.y, wB.z, wB.w};       \
    _Pragma("unroll") for (int j = 0; j < 8; ++j)                         \
        _Pragma("unroll") for (int i = 0; i < 8; ++i) a[j][i] +=          \
        xs[j] * ws[i];                                                    \
  }

// write silu(a) back to sX at cols {cb1..cb1+3, cb1+32..} x edges {eb1,eb2}
#define ACT_WRITE()                                                       \
  {                                                                       \
    _Pragma("unroll") for (int i = 0; i < 4; ++i) {                       \
      float4 v00 = {silu_f(a[0][i]), silu_f(a[1][i]), silu_f(a[2][i]),    \
                    silu_f(a[3][i])};                                     \
      float4 v10 = {silu_f(a[4][i]), silu_f(a[5][i]), silu_f(a[6][i]),    \
                    silu_f(a[7][i])};                                     \
      float4 v01 = {silu_f(a[0][4 + i]), silu_f(a[1][4 + i]),             \
                    silu_f(a[2][4 + i]), silu_f(a[3][4 + i])};            \
      float4 v11 = {silu_f(a[4][4 + i]), silu_f(a[5][4 + i]),             \
                    silu_f(a[6][4 + i]), silu_f(a[7][4 + i])};            \
      *(float4*)&sX[(cb1 + i) * SXT + eb1] = v00;                         \
      *(float4*)&sX[(cb1 + i) * SXT + eb2] = v10;                         \
      *(float4*)&sX[(cb1 + 32 + i) * SXT + eb1] = v01;                    \
      *(float4*)&sX[(cb1 + 32 + i) * SXT + eb2] = v11;                    \
    }                                                                     \
  }

// L1+L2+L3+L4 on one 128-edge tile. LDS: sX 33.8K + sW1 2K + sWW 32K ->
// 2 blocks/CU. L1-L3 on threads 0-127; L4 on threads 0-255 per 128-col half.
__global__ __launch_bounds__(512, 2) void mlp_all_k(
    const float* __restrict__ fc, const float* __restrict__ Wr1,
    const float* __restrict__ Wr2, const float* __restrict__ Wr3,
    const float* __restrict__ Wr4, const int* __restrict__ nact_p,
    float* __restrict__ Rbuf, int layer, int ecap) {
  __shared__ __attribute__((aligned(16))) float sX[64 * SXT];  // 33.8 KB [k][e]
  __shared__ __attribute__((aligned(16))) float sW1[8 * 64];
  __shared__ __attribute__((aligned(16))) float sWW[8192];     // 32 KB
  int nact = min(*nact_p, ecap);
  int t0 = blockIdx.x * ATILE;
  if (t0 >= nact || nact == 0) return;
  int tid = threadIdx.x;
  {
    const float* w1 = Wr1 + (size_t)layer * 512;
    const float* w2 = Wr2 + (size_t)layer * 4096;
    const float* w3 = Wr3 + (size_t)layer * 4096;
    if (tid < 512) sW1[tid] = w1[tid];
    for (int i = tid; i < 4096; i += 512) {
      sWW[i] = w2[i];
      sWW[4096 + i] = w3[i];
    }
    for (int i = tid; i < ATILE * 8; i += 512) {
      int el = i >> 3, k = i & 7;
      int e = min(t0 + el, nact - 1);
      sX[k * SXT + el] = fc[(size_t)e * 8 + k];
    }
  }
  __syncthreads();

  // ---- L1-L3 thread tile (threads 0-127)
  int eq = tid & 15, cq = tid >> 4;  // cq 0..7 for tid<128
  int eb1 = eq * 4, eb2 = eq * 4 + 64;
  int cb1 = cq * 4;  // pair col quad at cb1+32

  float a[8][8];
  if (tid < 128) {
    // ---- L1 (k = 0..7)
#pragma unroll
    for (int j = 0; j < 8; ++j)
#pragma unroll
      for (int i = 0; i < 8; ++i) a[j][i] = 0.f;
#pragma unroll
    for (int k = 0; k < 8; ++k) GEMM8x8_STEP(sW1, k, 32)
  }
  __syncthreads();  // (no-op hazard-wise for L1: sX rows 0..7 read above,
                    //  rows >=8 written below by same guard group)
  if (tid < 128) ACT_WRITE();
  __syncthreads();
  // ---- L2 (W2 = sWW[0:4096])
  if (tid < 128) {
#pragma unroll
    for (int j = 0; j < 8; ++j)
#pragma unroll
      for (int i = 0; i < 8; ++i) a[j][i] = 0.f;
#pragma unroll 4
    for (int k = 0; k < 64; ++k) GEMM8x8_STEP(sWW, k, 32)
  }
  __syncthreads();
  if (tid < 128) ACT_WRITE();
  __syncthreads();
  // ---- L3 (W3 = sWW[4096:8192])
  if (tid < 128) {
#pragma unroll
    for (int j = 0; j < 8; ++j)
#pragma unroll
      for (int i = 0; i < 8; ++i) a[j][i] = 0.f;
#pragma unroll 4
    for (int k = 0; k < 64; ++k) GEMM8x8_STEP(sWW + 4096, k, 32)
  }
  __syncthreads();
  if (tid < 128) ACT_WRITE();

  // ---- L4: 64 -> 256 over two 128-col halves; sWW reused as [k][128].
  // Threads 0-255: edges {4eq4,4eq4+64}, cols {4cq4, 4cq4+64} in the half.
  const float* w4 = Wr4 + (size_t)layer * 16384;
  int eq4 = tid & 15, cq4 = (tid >> 4) & 15;
  int e1 = eq4 * 4, e2 = eq4 * 4 + 64;
  int c1 = cq4 * 4;  // pair at c1+64
#pragma unroll
  for (int half = 0; half < 2; ++half) {
    __syncthreads();  // act writes done (h0) / prev half reads done (h1)
    for (int i = tid; i < 2048; i += 512) {
      int k = i >> 5, cc = (i & 31) * 4;
      *(float4*)&sWW[k * 128 + cc] =
          *(const float4*)&w4[k * 256 + half * 128 + cc];
    }
    __syncthreads();
    if (tid < 256) {
      float b[8][8];
#pragma unroll
      for (int j = 0; j < 8; ++j)
#pragma unroll
        for (int i = 0; i < 8; ++i) b[j][i] = 0.f;
#pragma unroll 2
      for (int k = 0; k < 64; ++k) {
        float4 xA = *(const float4*)&sX[k * SXT + e1];
        float4 xB = *(const float4*)&sX[k * SXT + e2];
        float4 wA = *(const float4*)&sWW[k * 128 + c1];
        float4 wB = *(const float4*)&sWW[k * 128 + c1 + 64];
        float xs[8] = {xA.x, xA.y, xA.z, xA.w, xB.x, xB.y, xB.z, xB.w};
        float ws[8] = {wA.x, wA.y, wA.z, wA.w, wB.x, wB.y, wB.z, wB.w};
#pragma unroll
        for (int j = 0; j < 8; ++j)
#pragma unroll
          for (int i = 0; i < 8; ++i) b[j][i] += xs[j] * ws[i];
      }
#pragma unroll
      for (int j = 0; j < 8; ++j) {
        int eg = t0 + (j < 4 ? e1 + j : e2 + j - 4);
        if (eg < nact) {
          float4 v0 = {b[j][0], b[j][1], b[j][2], b[j][3]};
          float4 v1 = {b[j][4], b[j][5], b[j][6], b[j][7]};
          *(float4*)&Rbuf[(size_t)eg * 256 + half * 128 + c1] = v0;
          *(float4*)&Rbuf[(size_t)eg * 256 + half * 128 + c1 + 64] = v1;
        }
      }
    }
  }
}

// ---------------------------------------------------------------- node layer
// Streams per-edge (R, hs, Y) with 4-edge load-phase ILP, accumulates
// acc[16], then node update (Wp from LDS) + per-node readout (NO atomics).
__global__ __launch_bounds__(512, 2) void gather_node_k(
    const float* __restrict__ h_in, float* __restrict__ h_out,
    const float* __restrict__ Rbuf, const float* __restrict__ Wsc,
    const float* __restrict__ Wp, const float* __restrict__ Wread,
    const float* __restrict__ Yc, const int* __restrict__ send,
    const int* __restrict__ off, const int* __restrict__ spec,
    float* __restrict__ eread, int N, int NE, int layer) {
  __shared__ __attribute__((aligned(16))) float sWp[4096];  // 16 KB
  __shared__ __attribute__((aligned(16))) float sVec[8][64];
  int tid = threadIdx.x;
  {
    const float* wp = Wp + (size_t)layer * 4096;
    for (int i = tid; i < 4096; i += 512) sWp[i] = wp[i];
  }
  __syncthreads();
  int wid = tid >> 6, lane = tid & 63;
  int n = blockIdx.x * 8 + wid;
  if (n >= N) return;

  int base = off[n];
  int deg = off[n + 1] - base;
  float acc[16];
#pragma unroll
  for (int i = 0; i < 16; ++i) acc[i] = 0.f;

  for (int b = 0; b < deg; b += 4) {
    int m = min(4, deg - b);
    int eu[4];
    float hs[4], r[4][4];
    // ---- load phase: independent vector loads in flight
#pragma unroll
    for (int j = 0; j < 4; ++j) {
      int e = base + b + (j < m ? j : m - 1);
      eu[j] = __builtin_amdgcn_readfirstlane(e);
      hs[j] = h_in[(size_t)send[eu[j]] * 64 + lane];
#pragma unroll
      for (int l = 0; l < 4; ++l)
        r[j][l] = Rbuf[(size_t)eu[j] * 256 + l * 64 + lane];
    }
    // ---- compute phase
#pragma unroll
    for (int j = 0; j < 4; ++j) {
      if (j < m) {  // wave-uniform
        const float* yp = Yc + (size_t)eu[j] * 16;  // uniform -> s_loads
        float t0_ = hs[j] * r[j][0], t1_ = hs[j] * r[j][1];
        float t2_ = hs[j] * r[j][2], t3_ = hs[j] * r[j][3];
        acc[0] += yp[0] * t0_;
        acc[1] += yp[1] * t1_;   acc[2] += yp[2] * t1_;   acc[3] += yp[3] * t1_;
        acc[4] += yp[4] * t2_;   acc[5] += yp[5] * t2_;   acc[6] += yp[6] * t2_;
        acc[7] += yp[7] * t2_;   acc[8] += yp[8] * t2_;
        acc[9] += yp[9] * t3_;   acc[10] += yp[10] * t3_;
        acc[11] += yp[11] * t3_; acc[12] += yp[12] * t3_;
        acc[13] += yp[13] * t3_; acc[14] += yp[14] * t3_;
        acc[15] += yp[15] * t3_;
      }
    }
  }

  // node update: inv = A0 + sum_lm A^2   (A = acc / 16)
  float inv = acc[0] * 0.0625f;
#pragma unroll
  for (int i = 0; i < 16; ++i) {
    float a2 = acc[i] * 0.0625f;
    inv += a2 * a2;
  }
  float* sv = sVec[wid];
  sv[lane] = inv;
  LDSFENCE();
  int sp = spec[n];
  const float* wsc = Wsc + ((size_t)layer * NE + sp) * 4096;
  const float* hold = h_in + (size_t)n * 64;
  float hv = 0.f;
#pragma unroll 4
  for (int k = 0; k < 64; ++k) {
    hv += sv[k] * sWp[k * 64 + lane];
    hv += hold[k] * wsc[k * 64 + lane];
  }
  h_out[(size_t)n * 64 + lane] = hv;
  LDSFENCE();
  sv[lane] = hv;
  LDSFENCE();
  if (lane < 3) {
    const float* wr = Wread + (size_t)layer * 64 * 3;
    float s = 0.f;
#pragma unroll 8
    for (int d = 0; d < 64; ++d) s += sv[d] * wr[d * 3 + lane];
    if (layer == 0)
      eread[(size_t)n * 4 + lane] = s;   // first layer: store (no memset)
    else
      eread[(size_t)n * 4 + lane] += s;  // private to this wave: no atomic
  }
}

// ---------------------------------------------------------------- energy out
// One block per graph; batch is sorted -> binary-search the segment.
__global__ __launch_bounds__(256) void reduce_energy_k(
    const float* __restrict__ node_e0, const float* __restrict__ eread,
    const int* __restrict__ batch, float* __restrict__ out, int N, int G) {
  __shared__ float red[256 * 4];
  int g = blockIdx.x;
  int tid = threadIdx.x;
  int lo = 0, hi = N;
  while (lo < hi) {
    int mid = (lo + hi) >> 1;
    if (batch[mid] < g) lo = mid + 1; else hi = mid;
  }
  int start = lo;
  hi = N;
  while (lo < hi) {
    int mid = (lo + hi) >> 1;
    if (batch[mid] < g + 1) lo = mid + 1; else hi = mid;
  }
  int end = lo;
  float p0 = 0.f, p1 = 0.f, p2 = 0.f;
  for (int n = start + tid; n < end; n += 256) {
    float e0 = node_e0[n];
    p0 += e0 + eread[(size_t)n * 4 + 0];
    p1 += e0 + eread[(size_t)n * 4 + 1];
    p2 += e0 + eread[(size_t)n * 4 + 2];
  }
  red[tid * 4 + 0] = p0;
  red[tid * 4 + 1] = p1;
  red[tid * 4 + 2] = p2;
  __syncthreads();
  for (int s = 128; s > 0; s >>= 1) {
    if (tid < s) {
      red[tid * 4 + 0] += red[(tid + s) * 4 + 0];
      red[tid * 4 + 1] += red[(tid + s) * 4 + 1];
      red[tid * 4 + 2] += red[(tid + s) * 4 + 2];
    }
    __syncthreads();
  }
  if (tid < 3) out[g * 3 + tid] = red[tid];
}

// ---------------------------------------------------------------- host
extern "C" void kernel_launch(void* const* d_in, const int* in_sizes, int n_in,
                              void* d_out, int out_size, void* d_ws,
                              size_t ws_size, hipStream_t stream) {
  const float* pos = (const float*)d_in[0];
  const float* shifts = (const float*)d_in[1];
  const float* attrs = (const float*)d_in[2];
  const float* ae = (const float*)d_in[3];
  const float* Wemb = (const float*)d_in[4];
  const float* Wr1 = (const float*)d_in[5];
  const float* Wr2 = (const float*)d_in[6];
  const float* Wr3 = (const float*)d_in[7];
  const float* Wr4 = (const float*)d_in[8];
  const float* Wsc = (const float*)d_in[9];
  const float* Wp = (const float*)d_in[10];
  const float* Wrd = (const float*)d_in[11];
  const int* ei = (const int*)d_in[12];
  const int* batch = (const int*)d_in[13];

  int N = in_sizes[0] / 3;
  int E = in_sizes[12] / 2;
  int NE = in_sizes[3];
  int nlayer = in_sizes[5] / (8 * 64);
  int G = out_size / 3;

  // adaptive edge capacity: fixed ~6 MB + 1124 B per edge
  size_t fixed = (size_t)N * 64 * 4 * 2 + (size_t)N * 4 * 7 + (1 << 20);
  int ecap = (int)((ws_size > fixed ? ws_size - fixed : 0) / 1124);
  if (ecap > ECAP_MAX) ecap = ECAP_MAX;

  char* w = (char*)d_ws;
  auto alloc = [&](size_t bytes) {
    void* p = (void*)w;
    w += (bytes + 255) & ~(size_t)255;
    return p;
  };
  float* h0 = (float*)alloc((size_t)N * 64 * 4);
  float* h1 = (float*)alloc((size_t)N * 64 * 4);
  float* Yc = (float*)alloc((size_t)ecap * 16 * 4);
  float* fc = (float*)alloc((size_t)ecap * 8 * 4);
  float* Rbuf = (float*)alloc((size_t)ecap * 256 * 4);
  int* send = (int*)alloc((size_t)ecap * 4);
  int* off = (int*)alloc((size_t)(N + 1) * 4);
  int* deg = (int*)alloc((size_t)N * 4);
  int* cur = (int*)alloc((size_t)N * 4);
  int* spec = (int*)alloc((size_t)N * 4);
  float* node_e0 = (float*)alloc((size_t)N * 4);
  float* eread = (float*)alloc((size_t)N * 4 * 4);

  clear_k<<<(N + 255) / 256, 256, 0, stream>>>(deg, cur, N);
  node_init_k<<<(N + 3) / 4, 256, 0, stream>>>(attrs, ae, Wemb, h0, spec,
                                               node_e0, N, NE);
  edge_count_k<<<(E + 255) / 256, 256, 0, stream>>>(pos, shifts, ei, deg, E);
  scan_deg_k<<<1, 1024, 0, stream>>>(deg, off, N);
  edge_fill_k<<<(E + 255) / 256, 256, 0, stream>>>(pos, shifts, ei, off, cur,
                                                   send, Yc, fc, E, ecap);
  const int* nact_p = off + N;
  float* hin = h0;
  float* hout = h1;
  for (int l = 0; l < nlayer; ++l) {
    mlp_all_k<<<(E + ATILE - 1) / ATILE, 512, 0, stream>>>(
        fc, Wr1, Wr2, Wr3, Wr4, nact_p, Rbuf, l, ecap);
    gather_node_k<<<(N + 7) / 8, 512, 0, stream>>>(hin, hout, Rbuf, Wsc, Wp,
                                                   Wrd, Yc, send, off, spec,
                                                   eread, N, NE, l);
    float* t = hin;
    hin = hout;
    hout = t;
  }
  reduce_energy_k<<<G, 256, 0, stream>>>(node_e0, eread, batch, (float*)d_out,
                                         N, G);
}